// Round 9
// baseline (260.904 us; speedup 1.0000x reference)
//
#include <hip/hip_runtime.h>
#include <math.h>

#define NMS_THR 0.3f
#define NACC 8   // accumulator waves in k_scan (block = (1+NACC)*64 threads)

__device__ __forceinline__ float fmul(float a, float b){ return __fmul_rn(a,b); }
__device__ __forceinline__ float fadd(float a, float b){ return __fadd_rn(a,b); }
__device__ __forceinline__ float fsub(float a, float b){ return __fsub_rn(a,b); }

// Raw barrier: LDS ordering only — does NOT drain vmcnt, so prefetches and
// row loads stay in flight across it (unlike __syncthreads).
#define BAR_LDS() asm volatile("s_waitcnt lgkmcnt(0)\n\ts_barrier" ::: "memory")

__device__ __forceinline__ unsigned long long rdlane64(unsigned long long v, int a) {
    unsigned long long l = (unsigned int)__builtin_amdgcn_readlane((int)(unsigned int)v, a);
    unsigned long long h = (unsigned int)__builtin_amdgcn_readlane((int)(unsigned int)(v >> 32), a);
    return (h << 32) | l;
}
__device__ __forceinline__ unsigned long long rfl64(unsigned long long x){
    unsigned int lo = (unsigned int)__builtin_amdgcn_readfirstlane((int)(unsigned int)x);
    unsigned int hi = (unsigned int)__builtin_amdgcn_readfirstlane((int)(unsigned int)(x >> 32));
    return ((unsigned long long)hi << 32) | lo;
}

// K1: per-row softmax max/sum + argmax + per-class regression decode. One wave per row.
__global__ __launch_bounds__(256) void k_decode(
    const float* __restrict__ prop, const float* __restrict__ reg,
    const float* __restrict__ clss, const float* __restrict__ stds,
    const int* __restrict__ imgsz,
    float* __restrict__ boxes, float* __restrict__ key,
    float* __restrict__ score, int* __restrict__ cls,
    int N, int C)
{
    int wid  = threadIdx.x >> 6;
    int lane = threadIdx.x & 63;
    int n = blockIdx.x * 4 + wid;
    if (n >= N) return;
    const float* row = clss + (long)n * C;
    float ninf = -__builtin_inff();
    float x0 = (lane < C)      ? row[lane]      : ninf;
    float x1 = (lane + 64 < C) ? row[lane + 64] : ninf;
    float m = fmaxf(x0, x1);
    for (int o = 32; o > 0; o >>= 1) m = fmaxf(m, __shfl_xor(m, o));
    float e0 = (lane < C)      ? expf(x0 - m) : 0.0f;
    float e1 = (lane + 64 < C) ? expf(x1 - m) : 0.0f;
    float s = e0 + e1;
    for (int o = 32; o > 0; o >>= 1) s += __shfl_xor(s, o);
    float bv; int bi;
    if (e0 >= e1) { bv = e0; bi = lane; } else { bv = e1; bi = lane + 64; }
    for (int o = 32; o > 0; o >>= 1) {
        float ov = __shfl_xor(bv, o);
        int   oi = __shfl_xor(bi, o);
        if (ov > bv || (ov == bv && oi < bi)) { bv = ov; bi = oi; }
    }
    if (lane == 0) {
        float sc = 1.0f / s;
        int   c  = bi;
        int   valid = (c != 0);
        float p0 = prop[n*4+0], p1 = prop[n*4+1], p2 = prop[n*4+2], p3 = prop[n*4+3];
        float w  = fsub(p2, p0), h = fsub(p3, p1);
        float cx = fadd(p0, fmul(0.5f, w));
        float cy = fadd(p1, fmul(0.5f, h));
        const float* rr = reg + (long)n * C * 4 + (long)c * 4;
        float t0 = fmul(rr[0], stds[0]);
        float t1 = fmul(rr[1], stds[1]);
        float t2 = fmul(rr[2], stds[2]);
        float t3 = fmul(rr[3], stds[3]);
        float px = fadd(cx, fmul(w, t0));
        float py = fadd(cy, fmul(h, t1));
        float pw = fmul(w, expf(t2));
        float ph = fmul(h, expf(t3));
        float hi = (float)(imgsz[0] - 1);
        float bx1 = fminf(fmaxf(fsub(px, fmul(0.5f, pw)), 0.0f), hi);
        float by1 = fminf(fmaxf(fsub(py, fmul(0.5f, ph)), 0.0f), hi);
        float bx2 = fminf(fmaxf(fadd(px, fmul(0.5f, pw)), 0.0f), hi);
        float by2 = fminf(fmaxf(fadd(py, fmul(0.5f, ph)), 0.0f), hi);
        boxes[n*4+0]=bx1; boxes[n*4+1]=by1; boxes[n*4+2]=bx2; boxes[n*4+3]=by2;
        score[n] = sc;
        cls[n]   = c;
        key[n]   = valid ? sc : ninf;
    }
}

// K2: stable descending rank sort. 64 rows/block, 4 j-strips of 256 threads.
// Block 0 additionally computes nValid (count of keys != -inf).
__global__ __launch_bounds__(256) void k_rank(
    const float* __restrict__ key, const float* __restrict__ boxes,
    float* __restrict__ boxesSorted, float* __restrict__ areaSorted,
    float* __restrict__ keySorted, int* __restrict__ rank,
    int* __restrict__ nValidPtr, int N)
{
    extern __shared__ float lkey[];     // N floats
    __shared__ int part[256];
    int tid = threadIdx.x;
    for (int j = tid; j < N; j += 256) lkey[j] = key[j];
    __syncthreads();

    int i = blockIdx.x * 64 + (tid & 63);
    int s = tid >> 6;
    int Q = (N + 3) >> 2;
    int r_part = 0;
    if (i < N) {
        float ki = lkey[i];
        int j0 = s * Q, j1 = min(N, j0 + Q);
        for (int j = j0; j < j1; ++j) {
            float kj = lkey[j];
            r_part += (kj > ki) || (kj == ki && j < i);   // stable
        }
    }
    part[tid] = r_part;
    __syncthreads();

    if (tid < 64 && i < N) {
        int r = part[tid] + part[tid+64] + part[tid+128] + part[tid+192];
        float ki = lkey[i];
        rank[i] = r;
        float b0 = boxes[i*4+0], b1 = boxes[i*4+1], b2 = boxes[i*4+2], b3 = boxes[i*4+3];
        boxesSorted[r*4+0]=b0; boxesSorted[r*4+1]=b1; boxesSorted[r*4+2]=b2; boxesSorted[r*4+3]=b3;
        areaSorted[r] = fmul(fsub(b2,b0), fsub(b3,b1));
        keySorted[r]  = ki;
    }

    if (blockIdx.x == 0) {
        __syncthreads();
        float ninf = -__builtin_inff();
        int inv = 0;
        for (int j = tid; j < N; j += 256) inv += (lkey[j] == ninf);
        part[tid] = inv;
        __syncthreads();
        if (tid == 0) {
            int t = 0;
            for (int q = 0; q < 256; ++q) t += part[q];
            nValidPtr[0] = N - t;
        }
    }
}

// K3: suppression bitmask, ROW-MAJOR padded: mask[i*Wpad + w]; rows 16B-aligned.
// dq[i*4 + d] = mask word (i>>6)+d of row i (d=0..3; 0 if out of range).
__global__ __launch_bounds__(256) void k_mask(
    const float* __restrict__ bs, const float* __restrict__ areas,
    const float* __restrict__ keySorted, unsigned long long* __restrict__ mask,
    unsigned long long* __restrict__ dq,
    int N, int W, int Wpad)
{
    int wid  = threadIdx.x >> 6;
    int lane = threadIdx.x & 63;
    int i = blockIdx.x * 4 + wid;
    if (i >= N) return;
    if (keySorted[i] == -__builtin_inff()) return;   // invalid row: never read
    float ax1 = bs[i*4+0], ay1 = bs[i*4+1], ax2 = bs[i*4+2], ay2 = bs[i*4+3];
    float aa  = areas[i];
    int w0 = i >> 6;
    if (lane == 0) {
        dq[i*4+0] = 0ULL; dq[i*4+1] = 0ULL; dq[i*4+2] = 0ULL; dq[i*4+3] = 0ULL;
    }
    for (int w = w0; w < W; ++w) {
        int j = w*64 + lane;
        int bit = 0;
        if (j < N && j > i) {
            float bx1 = bs[j*4+0], by1 = bs[j*4+1], bx2 = bs[j*4+2], by2 = bs[j*4+3];
            float ba  = areas[j];
            float ix1 = fmaxf(ax1,bx1), iy1 = fmaxf(ay1,by1);
            float ix2 = fminf(ax2,bx2), iy2 = fminf(ay2,by2);
            float iw = fmaxf(fsub(ix2,ix1), 0.0f);
            float ih = fmaxf(fsub(iy2,iy1), 0.0f);
            float inter = fmul(iw, ih);
            float denom = fadd(fsub(fadd(aa, ba), inter), 1e-9f);
            float iou = inter / denom;
            bit = (iou > NMS_THR) ? 1 : 0;
        }
        unsigned long long bm = __ballot(bit);
        if (lane == 0) {
            mask[(long)i*Wpad + w] = bm;
            int d = w - w0;
            if (d < 4) dq[i*4+d] = bm;
        }
    }
}

// K4: wave-specialized greedy scan, 128-row chunks. 1 resolver + NACC acc
// waves, raw lgkmcnt-only barriers. Resolver: pure SALU dependence chain
// (ctz -> readlane(A0/B0) -> andn); off-chain aggregates (candHi mask from
// A1, sacc from A2/A3/B1/B2) in separate pipelined readlane loops. Acc waves
// publish removed-map word pair via LDS ds_or single slots; keep words
// buffered in LDS, one cooperative global store at the end.
__global__ __launch_bounds__((NACC+1)*64, 1) void k_scan(
    const unsigned long long* __restrict__ mask,
    const unsigned long long* __restrict__ dq,
    const int* __restrict__ nValidPtr,
    int* __restrict__ keepSorted, int N, int W, int Wpad)
{
    __shared__ unsigned long long ldsSlotA, ldsSlotB;
    __shared__ unsigned long long ldsKeepBuf[128];   // keep words (W <= 128)
    int tid  = threadIdx.x;
    int wid  = tid >> 6;
    int lane = tid & 63;
    for (int i = tid; i < 128; i += (NACC+1)*64) ldsKeepBuf[i] = 0ULL;
    if (tid == 0) { ldsSlotA = 0ULL; ldsSlotB = 0ULL; }
    __syncthreads();

    int nValid  = __builtin_amdgcn_readfirstlane(nValidPtr[0]);
    int nChunks = (nValid + 127) >> 7;

    // resolver state: diagonal quads for current chunk
    unsigned long long A0=0,A1=0,A2=0,A3=0,B0=0,B1=0,B2=0,B3=0;
    unsigned long long sacc_prevA = 0ULL, sacc_prevB = 0ULL;
    if (wid == 0 && nChunks > 0) {
        int rA = lane, rB = 64 + lane;
        if (rA < N) {
            ulonglong2 a01 = *(const ulonglong2*)(dq + (size_t)rA*4);
            ulonglong2 a23 = *(const ulonglong2*)(dq + (size_t)rA*4 + 2);
            A0=a01.x; A1=a01.y; A2=a23.x; A3=a23.y;
        }
        if (rB < N) {
            ulonglong2 b01 = *(const ulonglong2*)(dq + (size_t)rB*4);
            ulonglong2 b23 = *(const ulonglong2*)(dq + (size_t)rB*4 + 2);
            B0=b01.x; B1=b01.y; B2=b23.x; B3=b23.y;
        }
    }
    // accumulator state: lane L owns words 2L, 2L+1
    unsigned long long accx = 0ULL, accy = 0ULL;
    bool accWave = (wid >= 1);
    int  accIdx  = wid - 1;                  // 0..NACC-1
    bool laneok  = (2*lane + 1 < Wpad);

    for (int c = 0; c < nChunks; ++c) {
        int base = c << 7;
        if (wid == 0) {
            // prefetch next chunk's quads (vmem, stays in flight across barriers)
            unsigned long long nA0=0,nA1=0,nA2=0,nA3=0,nB0=0,nB1=0,nB2=0,nB3=0;
            if (c + 1 < nChunks) {
                int rA = base + 128 + lane, rB = base + 192 + lane;
                if (rA < N) {
                    ulonglong2 a01 = *(const ulonglong2*)(dq + (size_t)rA*4);
                    ulonglong2 a23 = *(const ulonglong2*)(dq + (size_t)rA*4 + 2);
                    nA0=a01.x; nA1=a01.y; nA2=a23.x; nA3=a23.y;
                }
                if (rB < N) {
                    ulonglong2 b01 = *(const ulonglong2*)(dq + (size_t)rB*4);
                    ulonglong2 b23 = *(const ulonglong2*)(dq + (size_t)rB*4 + 2);
                    nB0=b01.x; nB1=b01.y; nB2=b23.x; nB3=b23.y;
                }
            }

            // read + zero partial slots (same-wave DS ops are program-ordered)
            unsigned long long pA = ldsSlotA, pB = ldsSlotB;
            if (lane == 0) { ldsSlotA = 0ULL; ldsSlotB = 0ULL; }
            unsigned long long incLo = rfl64(pA) | sacc_prevA;
            unsigned long long incHi = rfl64(pB) | sacc_prevB;
            int nv  = nValid - base;
            unsigned long long validLo = (nv >= 64) ? ~0ULL : ((1ULL << nv) - 1ULL);
            int nv2 = nv - 64;
            unsigned long long validHi = (nv2 >= 64) ? ~0ULL
                                        : (nv2 <= 0 ? 0ULL : ((1ULL << nv2) - 1ULL));
            unsigned long long candLo = validLo & ~incLo;
            unsigned long long candHi = validHi & ~incHi;
            unsigned long long keepLo = 0ULL, keepHi = 0ULL;

            // phase 1: pure dependence chain over first-half rows
            while (candLo) {
                int a = __builtin_ctzll(candLo);
                unsigned long long bit = 1ULL << a;
                keepLo |= bit;
                candLo &= ~bit & ~rdlane64(A0, a);
            }
            // aggregates over keepLo (independent readlanes, pipelined)
            unsigned long long mHi = 0ULL, sA = 0ULL, sB = 0ULL;
            {
                unsigned long long kb = keepLo;
                while (kb) {
                    int a = __builtin_ctzll(kb); kb &= kb - 1ULL;
                    mHi |= rdlane64(A1, a);
                    sA  |= rdlane64(A2, a);
                    sB  |= rdlane64(A3, a);
                }
            }
            candHi &= ~mHi;
            // phase 2: chain over second-half rows
            while (candHi) {
                int a = __builtin_ctzll(candHi);
                unsigned long long bit = 1ULL << a;
                keepHi |= bit;
                candHi &= ~bit & ~rdlane64(B0, a);
            }
            // aggregates over keepHi
            {
                unsigned long long kb = keepHi;
                while (kb) {
                    int a = __builtin_ctzll(kb); kb &= kb - 1ULL;
                    sA |= rdlane64(B1, a);
                    sB |= rdlane64(B2, a);
                }
            }
            sacc_prevA = sA; sacc_prevB = sB;
            if (lane == 0) {
                ldsKeepBuf[2*c]     = keepLo;
                ldsKeepBuf[2*c + 1] = keepHi;
            }
            A0=nA0; A1=nA1; A2=nA2; A3=nA3; B0=nB0; B1=nB1; B2=nB2; B3=nB3;
        }
        BAR_LDS();                             // barrier A (LDS-order only)
        unsigned long long kLo = ldsKeepBuf[2*c];
        unsigned long long kHi = ldsKeepBuf[2*c + 1];
        if (accWave && laneok && lane == c + 1) {  // publish words 2c+2, 2c+3
            atomicOr(&ldsSlotA, accx);
            atomicOr(&ldsSlotB, accy);
        }
        BAR_LDS();                             // barrier B
        if (accWave && laneok) {
            // 16-bit deal slice: wave accIdx owns keep bits [16k, 16k+16)
            unsigned int myb = (accIdx < 4)
                ? (unsigned int)((kLo >> (16*accIdx)) & 0xFFFFULL)
                : (unsigned int)((kHi >> (16*(accIdx-4))) & 0xFFFFULL);
            if (myb) {
                const unsigned long long* mb =
                    mask + (size_t)(base + 16*accIdx) * Wpad + 2*lane;
                unsigned int b = myb;
                int a0 = __builtin_ctz(b); b &= b - 1;
                int a1 = -1, a2 = -1, a3 = -1;
                if (b) { a1 = __builtin_ctz(b); b &= b - 1; }
                if (b) { a2 = __builtin_ctz(b); b &= b - 1; }
                if (b) { a3 = __builtin_ctz(b); b &= b - 1; }
                ulonglong2 v0 = {0,0}, v1 = {0,0}, v2 = {0,0}, v3 = {0,0};
                v0 = *(const ulonglong2*)(mb + (size_t)a0 * Wpad);
                if (a1 >= 0) v1 = *(const ulonglong2*)(mb + (size_t)a1 * Wpad);
                if (a2 >= 0) v2 = *(const ulonglong2*)(mb + (size_t)a2 * Wpad);
                if (a3 >= 0) v3 = *(const ulonglong2*)(mb + (size_t)a3 * Wpad);
                accx |= (v0.x | v1.x) | (v2.x | v3.x);
                accy |= (v0.y | v1.y) | (v2.y | v3.y);
                while (b) {                    // >4 kept in this slice (rare)
                    int a = __builtin_ctz(b); b &= b - 1;
                    ulonglong2 v = *(const ulonglong2*)(mb + (size_t)a * Wpad);
                    accx |= v.x; accy |= v.y;
                }
            }
        }
    }
    __syncthreads();
    // final cooperative keep write (covers all i < N; untouched words are 0)
    for (int i = tid; i < N; i += (NACC+1)*64)
        keepSorted[i] = (int)((ldsKeepBuf[i >> 6] >> (i & 63)) & 1ULL);
}

// K5: write outputs in original order: boxes*m, score*m, float(cls*keep).
__global__ __launch_bounds__(256) void k_out(
    const float* __restrict__ boxes, const float* __restrict__ score,
    const int* __restrict__ cls, const int* __restrict__ rank,
    const int* __restrict__ keepSorted,
    float* __restrict__ out, int N)
{
    int n = blockIdx.x * blockDim.x + threadIdx.x;
    if (n >= N) return;
    int k = keepSorted[rank[n]];
    float m = (float)k;
    out[n*4+0] = boxes[n*4+0]*m;
    out[n*4+1] = boxes[n*4+1]*m;
    out[n*4+2] = boxes[n*4+2]*m;
    out[n*4+3] = boxes[n*4+3]*m;
    out[(long)N*4 + n] = score[n]*m;
    out[(long)N*5 + n] = (float)(cls[n] * k);
}

extern "C" void kernel_launch(void* const* d_in, const int* in_sizes, int n_in,
                              void* d_out, int out_size, void* d_ws, size_t ws_size,
                              hipStream_t stream) {
    const float* prop = (const float*)d_in[0];
    const float* reg  = (const float*)d_in[1];
    const float* clss = (const float*)d_in[2];
    const float* stds = (const float*)d_in[3];
    const int*   img  = (const int*)d_in[4];

    int N = in_sizes[0] / 4;
    int C = in_sizes[2] / N;
    int W = (N + 63) / 64;
    int Wpad = (W + 1) & ~1;          // even -> 16B rows

    char* ws = (char*)d_ws;
    size_t off = 0;
    float* boxes       = (float*)(ws + off); off += (size_t)N*4*sizeof(float);
    float* key         = (float*)(ws + off); off += (size_t)N*sizeof(float);
    float* score       = (float*)(ws + off); off += (size_t)N*sizeof(float);
    int*   cls         = (int*)  (ws + off); off += (size_t)N*sizeof(int);
    int*   rank        = (int*)  (ws + off); off += (size_t)N*sizeof(int);
    float* boxesSorted = (float*)(ws + off); off += (size_t)N*4*sizeof(float);
    float* areaSorted  = (float*)(ws + off); off += (size_t)N*sizeof(float);
    float* keySorted   = (float*)(ws + off); off += (size_t)N*sizeof(float);
    int*   keepSorted  = (int*)  (ws + off); off += (size_t)N*sizeof(int);
    int*   nValid      = (int*)  (ws + off); off += sizeof(int);
    off = (off + 31) & ~(size_t)31;   // 32B-align dq / mask rows
    unsigned long long* dq    = (unsigned long long*)(ws + off);
    off += (size_t)N * 4 * sizeof(unsigned long long);
    unsigned long long* mask  = (unsigned long long*)(ws + off);
    off += (size_t)N * Wpad * sizeof(unsigned long long);
    (void)ws_size; (void)out_size; (void)n_in;

    int rowBlocks  = (N + 3) / 4;
    int thrBlocks  = (N + 255) / 256;
    int rankBlocks = (N + 63) / 64;

    k_decode<<<rowBlocks, 256, 0, stream>>>(prop, reg, clss, stds, img,
                                            boxes, key, score, cls, N, C);
    k_rank<<<rankBlocks, 256, (size_t)N*sizeof(float), stream>>>(key, boxes,
                                            boxesSorted, areaSorted, keySorted, rank, nValid, N);
    k_mask<<<rowBlocks, 256, 0, stream>>>(boxesSorted, areaSorted, keySorted,
                                          mask, dq, N, W, Wpad);
    k_scan<<<1, (NACC+1)*64, 0, stream>>>(mask, dq, nValid, keepSorted, N, W, Wpad);
    k_out<<<thrBlocks, 256, 0, stream>>>(boxes, score, cls, rank, keepSorted,
                                         (float*)d_out, N);
}

// Round 10
// 200.465 us; speedup vs baseline: 1.3015x; 1.3015x over previous
//
#include <hip/hip_runtime.h>
#include <math.h>

#define NMS_THR 0.3f
#define NACC 8   // accumulator waves in k_scan (block = (1+NACC)*64 threads)

__device__ __forceinline__ float fmul(float a, float b){ return __fmul_rn(a,b); }
__device__ __forceinline__ float fadd(float a, float b){ return __fadd_rn(a,b); }
__device__ __forceinline__ float fsub(float a, float b){ return __fsub_rn(a,b); }

// Raw barrier: LDS ordering only — does NOT drain vmcnt, so prefetches and
// row loads stay in flight across it (unlike __syncthreads).
#define BAR_LDS() asm volatile("s_waitcnt lgkmcnt(0)\n\ts_barrier" ::: "memory")

__device__ __forceinline__ unsigned long long rdlane64(unsigned long long v, int a) {
    unsigned long long l = (unsigned int)__builtin_amdgcn_readlane((int)(unsigned int)v, a);
    unsigned long long h = (unsigned int)__builtin_amdgcn_readlane((int)(unsigned int)(v >> 32), a);
    return (h << 32) | l;
}
__device__ __forceinline__ unsigned long long rfl64(unsigned long long x){
    unsigned int lo = (unsigned int)__builtin_amdgcn_readfirstlane((int)(unsigned int)x);
    unsigned int hi = (unsigned int)__builtin_amdgcn_readfirstlane((int)(unsigned int)(x >> 32));
    return ((unsigned long long)hi << 32) | lo;
}
__device__ __forceinline__ unsigned long long waveOr64(unsigned long long v){
    for (int o = 32; o > 0; o >>= 1) v |= __shfl_xor(v, o);
    return v;
}

// K1: per-row softmax max/sum + argmax + per-class regression decode. One wave per row.
__global__ __launch_bounds__(256) void k_decode(
    const float* __restrict__ prop, const float* __restrict__ reg,
    const float* __restrict__ clss, const float* __restrict__ stds,
    const int* __restrict__ imgsz,
    float* __restrict__ boxes, float* __restrict__ key,
    float* __restrict__ score, int* __restrict__ cls,
    int N, int C)
{
    int wid  = threadIdx.x >> 6;
    int lane = threadIdx.x & 63;
    int n = blockIdx.x * 4 + wid;
    if (n >= N) return;
    const float* row = clss + (long)n * C;
    float ninf = -__builtin_inff();
    float x0 = (lane < C)      ? row[lane]      : ninf;
    float x1 = (lane + 64 < C) ? row[lane + 64] : ninf;
    float m = fmaxf(x0, x1);
    for (int o = 32; o > 0; o >>= 1) m = fmaxf(m, __shfl_xor(m, o));
    float e0 = (lane < C)      ? expf(x0 - m) : 0.0f;
    float e1 = (lane + 64 < C) ? expf(x1 - m) : 0.0f;
    float s = e0 + e1;
    for (int o = 32; o > 0; o >>= 1) s += __shfl_xor(s, o);
    float bv; int bi;
    if (e0 >= e1) { bv = e0; bi = lane; } else { bv = e1; bi = lane + 64; }
    for (int o = 32; o > 0; o >>= 1) {
        float ov = __shfl_xor(bv, o);
        int   oi = __shfl_xor(bi, o);
        if (ov > bv || (ov == bv && oi < bi)) { bv = ov; bi = oi; }
    }
    if (lane == 0) {
        float sc = 1.0f / s;
        int   c  = bi;
        int   valid = (c != 0);
        float p0 = prop[n*4+0], p1 = prop[n*4+1], p2 = prop[n*4+2], p3 = prop[n*4+3];
        float w  = fsub(p2, p0), h = fsub(p3, p1);
        float cx = fadd(p0, fmul(0.5f, w));
        float cy = fadd(p1, fmul(0.5f, h));
        const float* rr = reg + (long)n * C * 4 + (long)c * 4;
        float t0 = fmul(rr[0], stds[0]);
        float t1 = fmul(rr[1], stds[1]);
        float t2 = fmul(rr[2], stds[2]);
        float t3 = fmul(rr[3], stds[3]);
        float px = fadd(cx, fmul(w, t0));
        float py = fadd(cy, fmul(h, t1));
        float pw = fmul(w, expf(t2));
        float ph = fmul(h, expf(t3));
        float hi = (float)(imgsz[0] - 1);
        float bx1 = fminf(fmaxf(fsub(px, fmul(0.5f, pw)), 0.0f), hi);
        float by1 = fminf(fmaxf(fsub(py, fmul(0.5f, ph)), 0.0f), hi);
        float bx2 = fminf(fmaxf(fadd(px, fmul(0.5f, pw)), 0.0f), hi);
        float by2 = fminf(fmaxf(fadd(py, fmul(0.5f, ph)), 0.0f), hi);
        boxes[n*4+0]=bx1; boxes[n*4+1]=by1; boxes[n*4+2]=bx2; boxes[n*4+3]=by2;
        score[n] = sc;
        cls[n]   = c;
        key[n]   = valid ? sc : ninf;
    }
}

// K2: stable descending rank sort. 64 rows/block, 4 j-strips of 256 threads.
// Block 0 additionally computes nValid (count of keys != -inf).
__global__ __launch_bounds__(256) void k_rank(
    const float* __restrict__ key, const float* __restrict__ boxes,
    float* __restrict__ boxesSorted, float* __restrict__ areaSorted,
    float* __restrict__ keySorted, int* __restrict__ rank,
    int* __restrict__ nValidPtr, int N)
{
    extern __shared__ float lkey[];     // N floats
    __shared__ int part[256];
    int tid = threadIdx.x;
    for (int j = tid; j < N; j += 256) lkey[j] = key[j];
    __syncthreads();

    int i = blockIdx.x * 64 + (tid & 63);
    int s = tid >> 6;
    int Q = (N + 3) >> 2;
    int r_part = 0;
    if (i < N) {
        float ki = lkey[i];
        int j0 = s * Q, j1 = min(N, j0 + Q);
        for (int j = j0; j < j1; ++j) {
            float kj = lkey[j];
            r_part += (kj > ki) || (kj == ki && j < i);   // stable
        }
    }
    part[tid] = r_part;
    __syncthreads();

    if (tid < 64 && i < N) {
        int r = part[tid] + part[tid+64] + part[tid+128] + part[tid+192];
        float ki = lkey[i];
        rank[i] = r;
        float b0 = boxes[i*4+0], b1 = boxes[i*4+1], b2 = boxes[i*4+2], b3 = boxes[i*4+3];
        boxesSorted[r*4+0]=b0; boxesSorted[r*4+1]=b1; boxesSorted[r*4+2]=b2; boxesSorted[r*4+3]=b3;
        areaSorted[r] = fmul(fsub(b2,b0), fsub(b3,b1));
        keySorted[r]  = ki;
    }

    if (blockIdx.x == 0) {
        __syncthreads();
        float ninf = -__builtin_inff();
        int inv = 0;
        for (int j = tid; j < N; j += 256) inv += (lkey[j] == ninf);
        part[tid] = inv;
        __syncthreads();
        if (tid == 0) {
            int t = 0;
            for (int q = 0; q < 256; ++q) t += part[q];
            nValidPtr[0] = N - t;
        }
    }
}

// K3: suppression bitmask, ROW-MAJOR padded: mask[i*Wpad + w]; rows 16B-aligned.
// dq[i*4 + d] = mask word (i>>6)+d of row i (d=0..3; 0 if out of range).
__global__ __launch_bounds__(256) void k_mask(
    const float* __restrict__ bs, const float* __restrict__ areas,
    const float* __restrict__ keySorted, unsigned long long* __restrict__ mask,
    unsigned long long* __restrict__ dq,
    int N, int W, int Wpad)
{
    int wid  = threadIdx.x >> 6;
    int lane = threadIdx.x & 63;
    int i = blockIdx.x * 4 + wid;
    if (i >= N) return;
    if (keySorted[i] == -__builtin_inff()) return;   // invalid row: never read
    float ax1 = bs[i*4+0], ay1 = bs[i*4+1], ax2 = bs[i*4+2], ay2 = bs[i*4+3];
    float aa  = areas[i];
    int w0 = i >> 6;
    if (lane == 0) {
        dq[i*4+0] = 0ULL; dq[i*4+1] = 0ULL; dq[i*4+2] = 0ULL; dq[i*4+3] = 0ULL;
    }
    for (int w = w0; w < W; ++w) {
        int j = w*64 + lane;
        int bit = 0;
        if (j < N && j > i) {
            float bx1 = bs[j*4+0], by1 = bs[j*4+1], bx2 = bs[j*4+2], by2 = bs[j*4+3];
            float ba  = areas[j];
            float ix1 = fmaxf(ax1,bx1), iy1 = fmaxf(ay1,by1);
            float ix2 = fminf(ax2,bx2), iy2 = fminf(ay2,by2);
            float iw = fmaxf(fsub(ix2,ix1), 0.0f);
            float ih = fmaxf(fsub(iy2,iy1), 0.0f);
            float inter = fmul(iw, ih);
            float denom = fadd(fsub(fadd(aa, ba), inter), 1e-9f);
            float iou = inter / denom;
            bit = (iou > NMS_THR) ? 1 : 0;
        }
        unsigned long long bm = __ballot(bit);
        if (lane == 0) {
            mask[(long)i*Wpad + w] = bm;
            int d = w - w0;
            if (d < 4) dq[i*4+d] = bm;
        }
    }
}

// K4: wave-specialized greedy scan, 128-row chunks (R8 skeleton). Resolver
// keep-chain carries ONLY rdlane64(A0/B0); aggregates (mHi from A1; sacc from
// A2/A3/B1/B2) computed per-chunk via masked wave-OR reductions. Acc waves:
// 16-bit deal slices, ulonglong2 row loads, ldsPart publish (same as R8).
// Fused output phase at the end (was k_out).
__global__ __launch_bounds__((NACC+1)*64, 1) void k_scan(
    const unsigned long long* __restrict__ mask,
    const unsigned long long* __restrict__ dq,
    const int* __restrict__ nValidPtr,
    int* __restrict__ keepSorted,
    const float* __restrict__ boxes, const float* __restrict__ score,
    const int* __restrict__ cls, const int* __restrict__ rank,
    float* __restrict__ out,
    int N, int W, int Wpad)
{
    __shared__ unsigned long long ldsPartA[NACC+1];
    __shared__ unsigned long long ldsPartB[NACC+1];
    __shared__ unsigned long long ldsKeepLo, ldsKeepHi;
    int tid  = threadIdx.x;
    int wid  = tid >> 6;
    int lane = tid & 63;
    for (int i = tid; i < N; i += (NACC+1)*64) keepSorted[i] = 0;
    if (tid <= NACC) { ldsPartA[tid] = 0ULL; ldsPartB[tid] = 0ULL; }
    if (tid == 0) { ldsKeepLo = 0ULL; ldsKeepHi = 0ULL; }
    __syncthreads();

    int nValid  = __builtin_amdgcn_readfirstlane(nValidPtr[0]);
    int nChunks = (nValid + 127) >> 7;

    // resolver state: diagonal quads for current chunk
    unsigned long long A0=0,A1=0,A2=0,A3=0,B0=0,B1=0,B2=0,B3=0;
    unsigned long long sacc_prevA = 0ULL, sacc_prevB = 0ULL;
    if (wid == 0 && nChunks > 0) {
        int rA = lane, rB = 64 + lane;
        if (rA < N) {
            ulonglong2 a01 = *(const ulonglong2*)(dq + (size_t)rA*4);
            ulonglong2 a23 = *(const ulonglong2*)(dq + (size_t)rA*4 + 2);
            A0=a01.x; A1=a01.y; A2=a23.x; A3=a23.y;
        }
        if (rB < N) {
            ulonglong2 b01 = *(const ulonglong2*)(dq + (size_t)rB*4);
            ulonglong2 b23 = *(const ulonglong2*)(dq + (size_t)rB*4 + 2);
            B0=b01.x; B1=b01.y; B2=b23.x; B3=b23.y;
        }
    }
    // accumulator state: lane L owns words 2L, 2L+1
    unsigned long long accx = 0ULL, accy = 0ULL;
    bool accWave = (wid >= 1);
    int  accIdx  = wid - 1;                  // 0..NACC-1
    bool laneok  = (2*lane + 1 < Wpad);

    for (int c = 0; c < nChunks; ++c) {
        int base = c << 7;
        if (wid == 0) {
            // prefetch next chunk's quads (vmem, stays in flight across barriers)
            unsigned long long nA0=0,nA1=0,nA2=0,nA3=0,nB0=0,nB1=0,nB2=0,nB3=0;
            if (c + 1 < nChunks) {
                int rA = base + 128 + lane, rB = base + 192 + lane;
                if (rA < N) {
                    ulonglong2 a01 = *(const ulonglong2*)(dq + (size_t)rA*4);
                    ulonglong2 a23 = *(const ulonglong2*)(dq + (size_t)rA*4 + 2);
                    nA0=a01.x; nA1=a01.y; nA2=a23.x; nA3=a23.y;
                }
                if (rB < N) {
                    ulonglong2 b01 = *(const ulonglong2*)(dq + (size_t)rB*4);
                    ulonglong2 b23 = *(const ulonglong2*)(dq + (size_t)rB*4 + 2);
                    nB0=b01.x; nB1=b01.y; nB2=b23.x; nB3=b23.y;
                }
            }

            unsigned long long pA = sacc_prevA, pB = sacc_prevB;
#pragma unroll
            for (int k = 1; k <= NACC; ++k) { pA |= ldsPartA[k]; pB |= ldsPartB[k]; }
            // uniform inc -> SALU resolve chain
            unsigned long long incLo = rfl64(pA), incHi = rfl64(pB);
            int nv  = nValid - base;
            unsigned long long validLo = (nv >= 64) ? ~0ULL : ((1ULL << nv) - 1ULL);
            int nv2 = nv - 64;
            unsigned long long validHi = (nv2 >= 64) ? ~0ULL
                                        : (nv2 <= 0 ? 0ULL : ((1ULL << nv2) - 1ULL));
            unsigned long long candLo = validLo & ~incLo;
            unsigned long long candHi = validHi & ~incHi;
            unsigned long long keepLo = 0ULL, keepHi = 0ULL;

            // phase 1: minimal dependence chain over first-half rows
            while (candLo) {
                int a = __builtin_ctzll(candLo);
                unsigned long long bit = 1ULL << a;
                keepLo |= bit;
                candLo &= ~bit & ~rdlane64(A0, a);
            }
            // mHi: masked wave-OR of A1 over kept lanes (once per chunk)
            {
                unsigned long long sel = ((keepLo >> lane) & 1ULL) ? A1 : 0ULL;
                candHi &= ~waveOr64(sel);
            }
            // phase 2: chain over second-half rows
            while (candHi) {
                int a = __builtin_ctzll(candHi);
                unsigned long long bit = 1ULL << a;
                keepHi |= bit;
                candHi &= ~bit & ~rdlane64(B0, a);
            }
            // sacc for next chunk: masked wave-ORs (off critical chain)
            {
                unsigned long long kL = (keepLo >> lane) & 1ULL;
                unsigned long long kH = (keepHi >> lane) & 1ULL;
                unsigned long long selA = (kL ? A2 : 0ULL) | (kH ? B1 : 0ULL);
                unsigned long long selB = (kL ? A3 : 0ULL) | (kH ? B2 : 0ULL);
                sacc_prevA = waveOr64(selA);
                sacc_prevB = waveOr64(selB);
            }
            if (lane == 0) { ldsKeepLo = keepLo; ldsKeepHi = keepHi; }
            if (base + lane < N)      keepSorted[base + lane]      = (int)((keepLo >> lane) & 1ULL);
            if (base + 64 + lane < N) keepSorted[base + 64 + lane] = (int)((keepHi >> lane) & 1ULL);
            A0=nA0; A1=nA1; A2=nA2; A3=nA3; B0=nB0; B1=nB1; B2=nB2; B3=nB3;
        }
        BAR_LDS();                             // barrier A (LDS-order only)
        unsigned long long kLo = ldsKeepLo;
        unsigned long long kHi = ldsKeepHi;
        if (accWave && laneok && lane == c + 1) {  // publish words 2c+2, 2c+3
            ldsPartA[wid] = accx;
            ldsPartB[wid] = accy;
        }
        BAR_LDS();                             // barrier B
        if (accWave && laneok) {
            // 16-bit deal slice: wave accIdx owns keep bits [16k, 16k+16)
            unsigned int myb = (accIdx < 4)
                ? (unsigned int)((kLo >> (16*accIdx)) & 0xFFFFULL)
                : (unsigned int)((kHi >> (16*(accIdx-4))) & 0xFFFFULL);
            if (myb) {
                const unsigned long long* mb =
                    mask + (size_t)(base + 16*accIdx) * Wpad + 2*lane;
                unsigned int b = myb;
                int a0 = __builtin_ctz(b); b &= b - 1;
                int a1 = -1, a2 = -1, a3 = -1;
                if (b) { a1 = __builtin_ctz(b); b &= b - 1; }
                if (b) { a2 = __builtin_ctz(b); b &= b - 1; }
                if (b) { a3 = __builtin_ctz(b); b &= b - 1; }
                ulonglong2 v0 = {0,0}, v1 = {0,0}, v2 = {0,0}, v3 = {0,0};
                v0 = *(const ulonglong2*)(mb + (size_t)a0 * Wpad);
                if (a1 >= 0) v1 = *(const ulonglong2*)(mb + (size_t)a1 * Wpad);
                if (a2 >= 0) v2 = *(const ulonglong2*)(mb + (size_t)a2 * Wpad);
                if (a3 >= 0) v3 = *(const ulonglong2*)(mb + (size_t)a3 * Wpad);
                accx |= (v0.x | v1.x) | (v2.x | v3.x);
                accy |= (v0.y | v1.y) | (v2.y | v3.y);
                while (b) {                    // >4 kept in this slice (rare)
                    int a = __builtin_ctz(b); b &= b - 1;
                    ulonglong2 v = *(const ulonglong2*)(mb + (size_t)a * Wpad);
                    accx |= v.x; accy |= v.y;
                }
            }
        }
    }

    // fused output phase (was k_out). __syncthreads drains resolver's keep
    // stores; same-CU loads are coherent after that.
    __syncthreads();
    for (int n = tid; n < N; n += (NACC+1)*64) {
        int k = keepSorted[rank[n]];
        float m = (float)k;
        out[n*4+0] = boxes[n*4+0]*m;
        out[n*4+1] = boxes[n*4+1]*m;
        out[n*4+2] = boxes[n*4+2]*m;
        out[n*4+3] = boxes[n*4+3]*m;
        out[(long)N*4 + n] = score[n]*m;
        out[(long)N*5 + n] = (float)(cls[n] * k);
    }
}

extern "C" void kernel_launch(void* const* d_in, const int* in_sizes, int n_in,
                              void* d_out, int out_size, void* d_ws, size_t ws_size,
                              hipStream_t stream) {
    const float* prop = (const float*)d_in[0];
    const float* reg  = (const float*)d_in[1];
    const float* clss = (const float*)d_in[2];
    const float* stds = (const float*)d_in[3];
    const int*   img  = (const int*)d_in[4];

    int N = in_sizes[0] / 4;
    int C = in_sizes[2] / N;
    int W = (N + 63) / 64;
    int Wpad = (W + 1) & ~1;          // even -> 16B rows

    char* ws = (char*)d_ws;
    size_t off = 0;
    float* boxes       = (float*)(ws + off); off += (size_t)N*4*sizeof(float);
    float* key         = (float*)(ws + off); off += (size_t)N*sizeof(float);
    float* score       = (float*)(ws + off); off += (size_t)N*sizeof(float);
    int*   cls         = (int*)  (ws + off); off += (size_t)N*sizeof(int);
    int*   rank        = (int*)  (ws + off); off += (size_t)N*sizeof(int);
    float* boxesSorted = (float*)(ws + off); off += (size_t)N*4*sizeof(float);
    float* areaSorted  = (float*)(ws + off); off += (size_t)N*sizeof(float);
    float* keySorted   = (float*)(ws + off); off += (size_t)N*sizeof(float);
    int*   keepSorted  = (int*)  (ws + off); off += (size_t)N*sizeof(int);
    int*   nValid      = (int*)  (ws + off); off += sizeof(int);
    off = (off + 31) & ~(size_t)31;   // 32B-align dq / mask rows
    unsigned long long* dq    = (unsigned long long*)(ws + off);
    off += (size_t)N * 4 * sizeof(unsigned long long);
    unsigned long long* mask  = (unsigned long long*)(ws + off);
    off += (size_t)N * Wpad * sizeof(unsigned long long);
    (void)ws_size; (void)out_size; (void)n_in;

    int rowBlocks  = (N + 3) / 4;
    int rankBlocks = (N + 63) / 64;

    k_decode<<<rowBlocks, 256, 0, stream>>>(prop, reg, clss, stds, img,
                                            boxes, key, score, cls, N, C);
    k_rank<<<rankBlocks, 256, (size_t)N*sizeof(float), stream>>>(key, boxes,
                                            boxesSorted, areaSorted, keySorted, rank, nValid, N);
    k_mask<<<rowBlocks, 256, 0, stream>>>(boxesSorted, areaSorted, keySorted,
                                          mask, dq, N, W, Wpad);
    k_scan<<<1, (NACC+1)*64, 0, stream>>>(mask, dq, nValid, keepSorted,
                                          boxes, score, cls, rank, (float*)d_out,
                                          N, W, Wpad);
}

// Round 11
// 187.177 us; speedup vs baseline: 1.3939x; 1.0710x over previous
//
#include <hip/hip_runtime.h>
#include <math.h>

#define NMS_THR 0.3f
#define NACC 8   // accumulator waves in k_scan (block = (1+NACC)*64 threads)

__device__ __forceinline__ float fmul(float a, float b){ return __fmul_rn(a,b); }
__device__ __forceinline__ float fadd(float a, float b){ return __fadd_rn(a,b); }
__device__ __forceinline__ float fsub(float a, float b){ return __fsub_rn(a,b); }

// Raw barrier: LDS ordering only — does NOT drain vmcnt, so prefetches and
// row loads stay in flight across it (unlike __syncthreads).
#define BAR_LDS() asm volatile("s_waitcnt lgkmcnt(0)\n\ts_barrier" ::: "memory")

__device__ __forceinline__ unsigned long long rdlane64(unsigned long long v, int a) {
    unsigned long long l = (unsigned int)__builtin_amdgcn_readlane((int)(unsigned int)v, a);
    unsigned long long h = (unsigned int)__builtin_amdgcn_readlane((int)(unsigned int)(v >> 32), a);
    return (h << 32) | l;
}
__device__ __forceinline__ unsigned long long rfl64(unsigned long long x){
    unsigned int lo = (unsigned int)__builtin_amdgcn_readfirstlane((int)(unsigned int)x);
    unsigned int hi = (unsigned int)__builtin_amdgcn_readfirstlane((int)(unsigned int)(x >> 32));
    return ((unsigned long long)hi << 32) | lo;
}
__device__ __forceinline__ unsigned long long waveOr64(unsigned long long v){
    for (int o = 32; o > 0; o >>= 1) v |= __shfl_xor(v, o);
    return v;
}

// K1: per-row softmax max/sum + argmax + per-class regression decode. One wave per row.
__global__ __launch_bounds__(256) void k_decode(
    const float* __restrict__ prop, const float* __restrict__ reg,
    const float* __restrict__ clss, const float* __restrict__ stds,
    const int* __restrict__ imgsz,
    float* __restrict__ boxes, float* __restrict__ key,
    float* __restrict__ score, int* __restrict__ cls,
    int N, int C)
{
    int wid  = threadIdx.x >> 6;
    int lane = threadIdx.x & 63;
    int n = blockIdx.x * 4 + wid;
    if (n >= N) return;
    const float* row = clss + (long)n * C;
    float ninf = -__builtin_inff();
    float x0 = (lane < C)      ? row[lane]      : ninf;
    float x1 = (lane + 64 < C) ? row[lane + 64] : ninf;
    float m = fmaxf(x0, x1);
    for (int o = 32; o > 0; o >>= 1) m = fmaxf(m, __shfl_xor(m, o));
    float e0 = (lane < C)      ? expf(x0 - m) : 0.0f;
    float e1 = (lane + 64 < C) ? expf(x1 - m) : 0.0f;
    float s = e0 + e1;
    for (int o = 32; o > 0; o >>= 1) s += __shfl_xor(s, o);
    float bv; int bi;
    if (e0 >= e1) { bv = e0; bi = lane; } else { bv = e1; bi = lane + 64; }
    for (int o = 32; o > 0; o >>= 1) {
        float ov = __shfl_xor(bv, o);
        int   oi = __shfl_xor(bi, o);
        if (ov > bv || (ov == bv && oi < bi)) { bv = ov; bi = oi; }
    }
    if (lane == 0) {
        float sc = 1.0f / s;
        int   c  = bi;
        int   valid = (c != 0);
        float p0 = prop[n*4+0], p1 = prop[n*4+1], p2 = prop[n*4+2], p3 = prop[n*4+3];
        float w  = fsub(p2, p0), h = fsub(p3, p1);
        float cx = fadd(p0, fmul(0.5f, w));
        float cy = fadd(p1, fmul(0.5f, h));
        const float* rr = reg + (long)n * C * 4 + (long)c * 4;
        float t0 = fmul(rr[0], stds[0]);
        float t1 = fmul(rr[1], stds[1]);
        float t2 = fmul(rr[2], stds[2]);
        float t3 = fmul(rr[3], stds[3]);
        float px = fadd(cx, fmul(w, t0));
        float py = fadd(cy, fmul(h, t1));
        float pw = fmul(w, expf(t2));
        float ph = fmul(h, expf(t3));
        float hi = (float)(imgsz[0] - 1);
        float bx1 = fminf(fmaxf(fsub(px, fmul(0.5f, pw)), 0.0f), hi);
        float by1 = fminf(fmaxf(fsub(py, fmul(0.5f, ph)), 0.0f), hi);
        float bx2 = fminf(fmaxf(fadd(px, fmul(0.5f, pw)), 0.0f), hi);
        float by2 = fminf(fmaxf(fadd(py, fmul(0.5f, ph)), 0.0f), hi);
        boxes[n*4+0]=bx1; boxes[n*4+1]=by1; boxes[n*4+2]=bx2; boxes[n*4+3]=by2;
        score[n] = sc;
        cls[n]   = c;
        key[n]   = valid ? sc : ninf;
    }
}

// K2: stable descending rank sort. 64 rows/block, 4 j-strips of 256 threads.
// Block 0 additionally computes nValid (count of keys != -inf).
__global__ __launch_bounds__(256) void k_rank(
    const float* __restrict__ key, const float* __restrict__ boxes,
    float* __restrict__ boxesSorted, float* __restrict__ areaSorted,
    float* __restrict__ keySorted, int* __restrict__ rank,
    int* __restrict__ nValidPtr, int N)
{
    extern __shared__ float lkey[];     // N floats
    __shared__ int part[256];
    int tid = threadIdx.x;
    for (int j = tid; j < N; j += 256) lkey[j] = key[j];
    __syncthreads();

    int i = blockIdx.x * 64 + (tid & 63);
    int s = tid >> 6;
    int Q = (N + 3) >> 2;
    int r_part = 0;
    if (i < N) {
        float ki = lkey[i];
        int j0 = s * Q, j1 = min(N, j0 + Q);
        for (int j = j0; j < j1; ++j) {
            float kj = lkey[j];
            r_part += (kj > ki) || (kj == ki && j < i);   // stable
        }
    }
    part[tid] = r_part;
    __syncthreads();

    if (tid < 64 && i < N) {
        int r = part[tid] + part[tid+64] + part[tid+128] + part[tid+192];
        float ki = lkey[i];
        rank[i] = r;
        float b0 = boxes[i*4+0], b1 = boxes[i*4+1], b2 = boxes[i*4+2], b3 = boxes[i*4+3];
        boxesSorted[r*4+0]=b0; boxesSorted[r*4+1]=b1; boxesSorted[r*4+2]=b2; boxesSorted[r*4+3]=b3;
        areaSorted[r] = fmul(fsub(b2,b0), fsub(b3,b1));
        keySorted[r]  = ki;
    }

    if (blockIdx.x == 0) {
        __syncthreads();
        float ninf = -__builtin_inff();
        int inv = 0;
        for (int j = tid; j < N; j += 256) inv += (lkey[j] == ninf);
        part[tid] = inv;
        __syncthreads();
        if (tid == 0) {
            int t = 0;
            for (int q = 0; q < 256; ++q) t += part[q];
            nValidPtr[0] = N - t;
        }
    }
}

// K3: suppression bitmask, ROW-MAJOR padded: mask[i*Wpad + w]; rows 16B-aligned.
// dq[i*4 + d] = mask word (i>>6)+d of row i (d=0..3; 0 if out of range).
__global__ __launch_bounds__(256) void k_mask(
    const float* __restrict__ bs, const float* __restrict__ areas,
    const float* __restrict__ keySorted, unsigned long long* __restrict__ mask,
    unsigned long long* __restrict__ dq,
    int N, int W, int Wpad)
{
    int wid  = threadIdx.x >> 6;
    int lane = threadIdx.x & 63;
    int i = blockIdx.x * 4 + wid;
    if (i >= N) return;
    if (keySorted[i] == -__builtin_inff()) return;   // invalid row: never read
    float ax1 = bs[i*4+0], ay1 = bs[i*4+1], ax2 = bs[i*4+2], ay2 = bs[i*4+3];
    float aa  = areas[i];
    int w0 = i >> 6;
    if (lane == 0) {
        dq[i*4+0] = 0ULL; dq[i*4+1] = 0ULL; dq[i*4+2] = 0ULL; dq[i*4+3] = 0ULL;
    }
    for (int w = w0; w < W; ++w) {
        int j = w*64 + lane;
        int bit = 0;
        if (j < N && j > i) {
            float bx1 = bs[j*4+0], by1 = bs[j*4+1], bx2 = bs[j*4+2], by2 = bs[j*4+3];
            float ba  = areas[j];
            float ix1 = fmaxf(ax1,bx1), iy1 = fmaxf(ay1,by1);
            float ix2 = fminf(ax2,bx2), iy2 = fminf(ay2,by2);
            float iw = fmaxf(fsub(ix2,ix1), 0.0f);
            float ih = fmaxf(fsub(iy2,iy1), 0.0f);
            float inter = fmul(iw, ih);
            float denom = fadd(fsub(fadd(aa, ba), inter), 1e-9f);
            float iou = inter / denom;
            bit = (iou > NMS_THR) ? 1 : 0;
        }
        unsigned long long bm = __ballot(bit);
        if (lane == 0) {
            mask[(long)i*Wpad + w] = bm;
            int d = w - w0;
            if (d < 4) dq[i*4+d] = bm;
        }
    }
}

// K4: wave-specialized greedy scan, 128-row chunks. Resolver uses 4-wide
// speculative batch resolve: extract 4 lowest candidate bits, issue all 8
// readlanes back-to-back (one VALU->SALU hazard per batch instead of per
// keep), then commit greedily in SALU against the accumulated rem of
// COMMITTED rows only — bit-identical to the serial chain. mHi (phase-1
// keeps' second-half suppression) accumulated in-batch from A1. sacc via
// masked wave-ORs. Acc waves identical to R8.
__global__ __launch_bounds__((NACC+1)*64, 1) void k_scan(
    const unsigned long long* __restrict__ mask,
    const unsigned long long* __restrict__ dq,
    const int* __restrict__ nValidPtr,
    int* __restrict__ keepSorted, int N, int W, int Wpad)
{
    __shared__ unsigned long long ldsPartA[NACC+1];
    __shared__ unsigned long long ldsPartB[NACC+1];
    __shared__ unsigned long long ldsKeepLo, ldsKeepHi;
    int tid  = threadIdx.x;
    int wid  = tid >> 6;
    int lane = tid & 63;
    for (int i = tid; i < N; i += (NACC+1)*64) keepSorted[i] = 0;
    if (tid <= NACC) { ldsPartA[tid] = 0ULL; ldsPartB[tid] = 0ULL; }
    if (tid == 0) { ldsKeepLo = 0ULL; ldsKeepHi = 0ULL; }
    __syncthreads();

    int nValid  = __builtin_amdgcn_readfirstlane(nValidPtr[0]);
    int nChunks = (nValid + 127) >> 7;

    // resolver state: diagonal quads for current chunk
    unsigned long long A0=0,A1=0,A2=0,A3=0,B0=0,B1=0,B2=0,B3=0;
    unsigned long long sacc_prevA = 0ULL, sacc_prevB = 0ULL;
    if (wid == 0 && nChunks > 0) {
        int rA = lane, rB = 64 + lane;
        if (rA < N) {
            ulonglong2 a01 = *(const ulonglong2*)(dq + (size_t)rA*4);
            ulonglong2 a23 = *(const ulonglong2*)(dq + (size_t)rA*4 + 2);
            A0=a01.x; A1=a01.y; A2=a23.x; A3=a23.y;
        }
        if (rB < N) {
            ulonglong2 b01 = *(const ulonglong2*)(dq + (size_t)rB*4);
            ulonglong2 b23 = *(const ulonglong2*)(dq + (size_t)rB*4 + 2);
            B0=b01.x; B1=b01.y; B2=b23.x; B3=b23.y;
        }
    }
    // accumulator state: lane L owns words 2L, 2L+1
    unsigned long long accx = 0ULL, accy = 0ULL;
    bool accWave = (wid >= 1);
    int  accIdx  = wid - 1;                  // 0..NACC-1
    bool laneok  = (2*lane + 1 < Wpad);

    for (int c = 0; c < nChunks; ++c) {
        int base = c << 7;
        if (wid == 0) {
            // prefetch next chunk's quads (vmem, stays in flight across barriers)
            unsigned long long nA0=0,nA1=0,nA2=0,nA3=0,nB0=0,nB1=0,nB2=0,nB3=0;
            if (c + 1 < nChunks) {
                int rA = base + 128 + lane, rB = base + 192 + lane;
                if (rA < N) {
                    ulonglong2 a01 = *(const ulonglong2*)(dq + (size_t)rA*4);
                    ulonglong2 a23 = *(const ulonglong2*)(dq + (size_t)rA*4 + 2);
                    nA0=a01.x; nA1=a01.y; nA2=a23.x; nA3=a23.y;
                }
                if (rB < N) {
                    ulonglong2 b01 = *(const ulonglong2*)(dq + (size_t)rB*4);
                    ulonglong2 b23 = *(const ulonglong2*)(dq + (size_t)rB*4 + 2);
                    nB0=b01.x; nB1=b01.y; nB2=b23.x; nB3=b23.y;
                }
            }

            unsigned long long pA = sacc_prevA, pB = sacc_prevB;
#pragma unroll
            for (int k = 1; k <= NACC; ++k) { pA |= ldsPartA[k]; pB |= ldsPartB[k]; }
            unsigned long long incLo = rfl64(pA), incHi = rfl64(pB);
            int nv  = nValid - base;
            unsigned long long validLo = (nv >= 64) ? ~0ULL : ((1ULL << nv) - 1ULL);
            int nv2 = nv - 64;
            unsigned long long validHi = (nv2 >= 64) ? ~0ULL
                                        : (nv2 <= 0 ? 0ULL : ((1ULL << nv2) - 1ULL));
            unsigned long long candLo = validLo & ~incLo;
            unsigned long long candHi = validHi & ~incHi;
            unsigned long long keepLo = 0ULL, keepHi = 0ULL;

            // phase 1: 4-wide batch resolve over first-half rows
            unsigned long long mHiAcc = 0ULL;
            while (candLo) {
                unsigned long long t = candLo;
                int a0 = __builtin_ctzll(t); t &= t - 1;
                int a1 = t ? __builtin_ctzll(t) : a0; t &= t - 1;
                int a2 = t ? __builtin_ctzll(t) : a0; t &= t - 1;
                int a3 = t ? __builtin_ctzll(t) : a0;
                unsigned long long m0 = rdlane64(A0, a0), m1 = rdlane64(A0, a1);
                unsigned long long m2 = rdlane64(A0, a2), m3 = rdlane64(A0, a3);
                unsigned long long n0 = rdlane64(A1, a0), n1 = rdlane64(A1, a1);
                unsigned long long n2 = rdlane64(A1, a2), n3 = rdlane64(A1, a3);
                unsigned long long rem  = m0 | (1ULL << a0);
                unsigned long long kept = 1ULL << a0;
                unsigned long long hi   = n0;
                unsigned long long b;
                b = 1ULL << a1; if (!(rem & b)) { rem |= m1 | b; kept |= b; hi |= n1; }
                b = 1ULL << a2; if (!(rem & b)) { rem |= m2 | b; kept |= b; hi |= n2; }
                b = 1ULL << a3; if (!(rem & b)) { rem |= m3 | b; kept |= b; hi |= n3; }
                keepLo |= kept; mHiAcc |= hi;
                candLo &= ~rem;
            }
            candHi &= ~mHiAcc;
            // phase 2: 4-wide batch resolve over second-half rows
            while (candHi) {
                unsigned long long t = candHi;
                int a0 = __builtin_ctzll(t); t &= t - 1;
                int a1 = t ? __builtin_ctzll(t) : a0; t &= t - 1;
                int a2 = t ? __builtin_ctzll(t) : a0; t &= t - 1;
                int a3 = t ? __builtin_ctzll(t) : a0;
                unsigned long long m0 = rdlane64(B0, a0), m1 = rdlane64(B0, a1);
                unsigned long long m2 = rdlane64(B0, a2), m3 = rdlane64(B0, a3);
                unsigned long long rem  = m0 | (1ULL << a0);
                unsigned long long kept = 1ULL << a0;
                unsigned long long b;
                b = 1ULL << a1; if (!(rem & b)) { rem |= m1 | b; kept |= b; }
                b = 1ULL << a2; if (!(rem & b)) { rem |= m2 | b; kept |= b; }
                b = 1ULL << a3; if (!(rem & b)) { rem |= m3 | b; kept |= b; }
                keepHi |= kept;
                candHi &= ~rem;
            }
            // sacc for next chunk: masked wave-ORs (off critical chain)
            {
                unsigned long long kL = (keepLo >> lane) & 1ULL;
                unsigned long long kH = (keepHi >> lane) & 1ULL;
                unsigned long long selA = (kL ? A2 : 0ULL) | (kH ? B1 : 0ULL);
                unsigned long long selB = (kL ? A3 : 0ULL) | (kH ? B2 : 0ULL);
                sacc_prevA = waveOr64(selA);
                sacc_prevB = waveOr64(selB);
            }
            if (lane == 0) { ldsKeepLo = keepLo; ldsKeepHi = keepHi; }
            if (base + lane < N)      keepSorted[base + lane]      = (int)((keepLo >> lane) & 1ULL);
            if (base + 64 + lane < N) keepSorted[base + 64 + lane] = (int)((keepHi >> lane) & 1ULL);
            A0=nA0; A1=nA1; A2=nA2; A3=nA3; B0=nB0; B1=nB1; B2=nB2; B3=nB3;
        }
        BAR_LDS();                             // barrier A (LDS-order only)
        unsigned long long kLo = ldsKeepLo;
        unsigned long long kHi = ldsKeepHi;
        if (accWave && laneok && lane == c + 1) {  // publish words 2c+2, 2c+3
            ldsPartA[wid] = accx;
            ldsPartB[wid] = accy;
        }
        BAR_LDS();                             // barrier B
        if (accWave && laneok) {
            // 16-bit deal slice: wave accIdx owns keep bits [16k, 16k+16)
            unsigned int myb = (accIdx < 4)
                ? (unsigned int)((kLo >> (16*accIdx)) & 0xFFFFULL)
                : (unsigned int)((kHi >> (16*(accIdx-4))) & 0xFFFFULL);
            if (myb) {
                const unsigned long long* mb =
                    mask + (size_t)(base + 16*accIdx) * Wpad + 2*lane;
                unsigned int b = myb;
                int a0 = __builtin_ctz(b); b &= b - 1;
                int a1 = -1, a2 = -1, a3 = -1;
                if (b) { a1 = __builtin_ctz(b); b &= b - 1; }
                if (b) { a2 = __builtin_ctz(b); b &= b - 1; }
                if (b) { a3 = __builtin_ctz(b); b &= b - 1; }
                ulonglong2 v0 = {0,0}, v1 = {0,0}, v2 = {0,0}, v3 = {0,0};
                v0 = *(const ulonglong2*)(mb + (size_t)a0 * Wpad);
                if (a1 >= 0) v1 = *(const ulonglong2*)(mb + (size_t)a1 * Wpad);
                if (a2 >= 0) v2 = *(const ulonglong2*)(mb + (size_t)a2 * Wpad);
                if (a3 >= 0) v3 = *(const ulonglong2*)(mb + (size_t)a3 * Wpad);
                accx |= (v0.x | v1.x) | (v2.x | v3.x);
                accy |= (v0.y | v1.y) | (v2.y | v3.y);
                while (b) {                    // >4 kept in this slice (rare)
                    int a = __builtin_ctz(b); b &= b - 1;
                    ulonglong2 v = *(const ulonglong2*)(mb + (size_t)a * Wpad);
                    accx |= v.x; accy |= v.y;
                }
            }
        }
    }
}

// K5: write outputs in original order: boxes*m, score*m, float(cls*keep).
__global__ __launch_bounds__(256) void k_out(
    const float* __restrict__ boxes, const float* __restrict__ score,
    const int* __restrict__ cls, const int* __restrict__ rank,
    const int* __restrict__ keepSorted,
    float* __restrict__ out, int N)
{
    int n = blockIdx.x * blockDim.x + threadIdx.x;
    if (n >= N) return;
    int k = keepSorted[rank[n]];
    float m = (float)k;
    out[n*4+0] = boxes[n*4+0]*m;
    out[n*4+1] = boxes[n*4+1]*m;
    out[n*4+2] = boxes[n*4+2]*m;
    out[n*4+3] = boxes[n*4+3]*m;
    out[(long)N*4 + n] = score[n]*m;
    out[(long)N*5 + n] = (float)(cls[n] * k);
}

extern "C" void kernel_launch(void* const* d_in, const int* in_sizes, int n_in,
                              void* d_out, int out_size, void* d_ws, size_t ws_size,
                              hipStream_t stream) {
    const float* prop = (const float*)d_in[0];
    const float* reg  = (const float*)d_in[1];
    const float* clss = (const float*)d_in[2];
    const float* stds = (const float*)d_in[3];
    const int*   img  = (const int*)d_in[4];

    int N = in_sizes[0] / 4;
    int C = in_sizes[2] / N;
    int W = (N + 63) / 64;
    int Wpad = (W + 1) & ~1;          // even -> 16B rows

    char* ws = (char*)d_ws;
    size_t off = 0;
    float* boxes       = (float*)(ws + off); off += (size_t)N*4*sizeof(float);
    float* key         = (float*)(ws + off); off += (size_t)N*sizeof(float);
    float* score       = (float*)(ws + off); off += (size_t)N*sizeof(float);
    int*   cls         = (int*)  (ws + off); off += (size_t)N*sizeof(int);
    int*   rank        = (int*)  (ws + off); off += (size_t)N*sizeof(int);
    float* boxesSorted = (float*)(ws + off); off += (size_t)N*4*sizeof(float);
    float* areaSorted  = (float*)(ws + off); off += (size_t)N*sizeof(float);
    float* keySorted   = (float*)(ws + off); off += (size_t)N*sizeof(float);
    int*   keepSorted  = (int*)  (ws + off); off += (size_t)N*sizeof(int);
    int*   nValid      = (int*)  (ws + off); off += sizeof(int);
    off = (off + 31) & ~(size_t)31;   // 32B-align dq / mask rows
    unsigned long long* dq    = (unsigned long long*)(ws + off);
    off += (size_t)N * 4 * sizeof(unsigned long long);
    unsigned long long* mask  = (unsigned long long*)(ws + off);
    off += (size_t)N * Wpad * sizeof(unsigned long long);
    (void)ws_size; (void)out_size; (void)n_in;

    int rowBlocks  = (N + 3) / 4;
    int thrBlocks  = (N + 255) / 256;
    int rankBlocks = (N + 63) / 64;

    k_decode<<<rowBlocks, 256, 0, stream>>>(prop, reg, clss, stds, img,
                                            boxes, key, score, cls, N, C);
    k_rank<<<rankBlocks, 256, (size_t)N*sizeof(float), stream>>>(key, boxes,
                                            boxesSorted, areaSorted, keySorted, rank, nValid, N);
    k_mask<<<rowBlocks, 256, 0, stream>>>(boxesSorted, areaSorted, keySorted,
                                          mask, dq, N, W, Wpad);
    k_scan<<<1, (NACC+1)*64, 0, stream>>>(mask, dq, nValid, keepSorted, N, W, Wpad);
    k_out<<<thrBlocks, 256, 0, stream>>>(boxes, score, cls, rank, keepSorted,
                                         (float*)d_out, N);
}

// Round 12
// 185.940 us; speedup vs baseline: 1.4032x; 1.0067x over previous
//
#include <hip/hip_runtime.h>
#include <math.h>

#define NMS_THR 0.3f
#define NACC 8   // accumulator waves in k_scan (block = (1+NACC)*64 threads)

__device__ __forceinline__ float fmul(float a, float b){ return __fmul_rn(a,b); }
__device__ __forceinline__ float fadd(float a, float b){ return __fadd_rn(a,b); }
__device__ __forceinline__ float fsub(float a, float b){ return __fsub_rn(a,b); }

// Raw barrier: LDS ordering only — does NOT drain vmcnt, so prefetches and
// row loads stay in flight across it (unlike __syncthreads).
#define BAR_LDS() asm volatile("s_waitcnt lgkmcnt(0)\n\ts_barrier" ::: "memory")

__device__ __forceinline__ unsigned long long rdlane64(unsigned long long v, int a) {
    unsigned long long l = (unsigned int)__builtin_amdgcn_readlane((int)(unsigned int)v, a);
    unsigned long long h = (unsigned int)__builtin_amdgcn_readlane((int)(unsigned int)(v >> 32), a);
    return (h << 32) | l;
}
__device__ __forceinline__ unsigned long long rfl64(unsigned long long x){
    unsigned int lo = (unsigned int)__builtin_amdgcn_readfirstlane((int)(unsigned int)x);
    unsigned int hi = (unsigned int)__builtin_amdgcn_readfirstlane((int)(unsigned int)(x >> 32));
    return ((unsigned long long)hi << 32) | lo;
}
__device__ __forceinline__ unsigned long long waveOr64(unsigned long long v){
    for (int o = 32; o > 0; o >>= 1) v |= __shfl_xor(v, o);
    return v;
}

// K1: per-row softmax max/sum + argmax + per-class regression decode. One wave per row.
__global__ __launch_bounds__(256) void k_decode(
    const float* __restrict__ prop, const float* __restrict__ reg,
    const float* __restrict__ clss, const float* __restrict__ stds,
    const int* __restrict__ imgsz,
    float* __restrict__ boxes, float* __restrict__ key,
    float* __restrict__ score, int* __restrict__ cls,
    int N, int C)
{
    int wid  = threadIdx.x >> 6;
    int lane = threadIdx.x & 63;
    int n = blockIdx.x * 4 + wid;
    if (n >= N) return;
    const float* row = clss + (long)n * C;
    float ninf = -__builtin_inff();
    float x0 = (lane < C)      ? row[lane]      : ninf;
    float x1 = (lane + 64 < C) ? row[lane + 64] : ninf;
    float m = fmaxf(x0, x1);
    for (int o = 32; o > 0; o >>= 1) m = fmaxf(m, __shfl_xor(m, o));
    float e0 = (lane < C)      ? expf(x0 - m) : 0.0f;
    float e1 = (lane + 64 < C) ? expf(x1 - m) : 0.0f;
    float s = e0 + e1;
    for (int o = 32; o > 0; o >>= 1) s += __shfl_xor(s, o);
    float bv; int bi;
    if (e0 >= e1) { bv = e0; bi = lane; } else { bv = e1; bi = lane + 64; }
    for (int o = 32; o > 0; o >>= 1) {
        float ov = __shfl_xor(bv, o);
        int   oi = __shfl_xor(bi, o);
        if (ov > bv || (ov == bv && oi < bi)) { bv = ov; bi = oi; }
    }
    if (lane == 0) {
        float sc = 1.0f / s;
        int   c  = bi;
        int   valid = (c != 0);
        float p0 = prop[n*4+0], p1 = prop[n*4+1], p2 = prop[n*4+2], p3 = prop[n*4+3];
        float w  = fsub(p2, p0), h = fsub(p3, p1);
        float cx = fadd(p0, fmul(0.5f, w));
        float cy = fadd(p1, fmul(0.5f, h));
        const float* rr = reg + (long)n * C * 4 + (long)c * 4;
        float t0 = fmul(rr[0], stds[0]);
        float t1 = fmul(rr[1], stds[1]);
        float t2 = fmul(rr[2], stds[2]);
        float t3 = fmul(rr[3], stds[3]);
        float px = fadd(cx, fmul(w, t0));
        float py = fadd(cy, fmul(h, t1));
        float pw = fmul(w, expf(t2));
        float ph = fmul(h, expf(t3));
        float hi = (float)(imgsz[0] - 1);
        float bx1 = fminf(fmaxf(fsub(px, fmul(0.5f, pw)), 0.0f), hi);
        float by1 = fminf(fmaxf(fsub(py, fmul(0.5f, ph)), 0.0f), hi);
        float bx2 = fminf(fmaxf(fadd(px, fmul(0.5f, pw)), 0.0f), hi);
        float by2 = fminf(fmaxf(fadd(py, fmul(0.5f, ph)), 0.0f), hi);
        boxes[n*4+0]=bx1; boxes[n*4+1]=by1; boxes[n*4+2]=bx2; boxes[n*4+3]=by2;
        score[n] = sc;
        cls[n]   = c;
        key[n]   = valid ? sc : ninf;
    }
}

// K2: stable descending rank sort. 64 rows/block, 4 j-strips of 256 threads.
// Block 0 additionally computes nValid (count of keys != -inf).
__global__ __launch_bounds__(256) void k_rank(
    const float* __restrict__ key, const float* __restrict__ boxes,
    float* __restrict__ boxesSorted, float* __restrict__ areaSorted,
    float* __restrict__ keySorted, int* __restrict__ rank,
    int* __restrict__ nValidPtr, int N)
{
    extern __shared__ float lkey[];     // N floats
    __shared__ int part[256];
    int tid = threadIdx.x;
    for (int j = tid; j < N; j += 256) lkey[j] = key[j];
    __syncthreads();

    int i = blockIdx.x * 64 + (tid & 63);
    int s = tid >> 6;
    int Q = (N + 3) >> 2;
    int r_part = 0;
    if (i < N) {
        float ki = lkey[i];
        int j0 = s * Q, j1 = min(N, j0 + Q);
        for (int j = j0; j < j1; ++j) {
            float kj = lkey[j];
            r_part += (kj > ki) || (kj == ki && j < i);   // stable
        }
    }
    part[tid] = r_part;
    __syncthreads();

    if (tid < 64 && i < N) {
        int r = part[tid] + part[tid+64] + part[tid+128] + part[tid+192];
        float ki = lkey[i];
        rank[i] = r;
        float b0 = boxes[i*4+0], b1 = boxes[i*4+1], b2 = boxes[i*4+2], b3 = boxes[i*4+3];
        boxesSorted[r*4+0]=b0; boxesSorted[r*4+1]=b1; boxesSorted[r*4+2]=b2; boxesSorted[r*4+3]=b3;
        areaSorted[r] = fmul(fsub(b2,b0), fsub(b3,b1));
        keySorted[r]  = ki;
    }

    if (blockIdx.x == 0) {
        __syncthreads();
        float ninf = -__builtin_inff();
        int inv = 0;
        for (int j = tid; j < N; j += 256) inv += (lkey[j] == ninf);
        part[tid] = inv;
        __syncthreads();
        if (tid == 0) {
            int t = 0;
            for (int q = 0; q < 256; ++q) t += part[q];
            nValidPtr[0] = N - t;
        }
    }
}

// K3: suppression bitmask, ROW-MAJOR padded: mask[i*Wpad + w]; rows 16B-aligned.
// dq[i*4 + d] = mask word (i>>6)+d of row i (d=0..3; 0 if out of range).
__global__ __launch_bounds__(256) void k_mask(
    const float* __restrict__ bs, const float* __restrict__ areas,
    const float* __restrict__ keySorted, unsigned long long* __restrict__ mask,
    unsigned long long* __restrict__ dq,
    int N, int W, int Wpad)
{
    int wid  = threadIdx.x >> 6;
    int lane = threadIdx.x & 63;
    int i = blockIdx.x * 4 + wid;
    if (i >= N) return;
    if (keySorted[i] == -__builtin_inff()) return;   // invalid row: never read
    float ax1 = bs[i*4+0], ay1 = bs[i*4+1], ax2 = bs[i*4+2], ay2 = bs[i*4+3];
    float aa  = areas[i];
    int w0 = i >> 6;
    if (lane == 0) {
        dq[i*4+0] = 0ULL; dq[i*4+1] = 0ULL; dq[i*4+2] = 0ULL; dq[i*4+3] = 0ULL;
    }
    for (int w = w0; w < W; ++w) {
        int j = w*64 + lane;
        int bit = 0;
        if (j < N && j > i) {
            float bx1 = bs[j*4+0], by1 = bs[j*4+1], bx2 = bs[j*4+2], by2 = bs[j*4+3];
            float ba  = areas[j];
            float ix1 = fmaxf(ax1,bx1), iy1 = fmaxf(ay1,by1);
            float ix2 = fminf(ax2,bx2), iy2 = fminf(ay2,by2);
            float iw = fmaxf(fsub(ix2,ix1), 0.0f);
            float ih = fmaxf(fsub(iy2,iy1), 0.0f);
            float inter = fmul(iw, ih);
            float denom = fadd(fsub(fadd(aa, ba), inter), 1e-9f);
            float iou = inter / denom;
            bit = (iou > NMS_THR) ? 1 : 0;
        }
        unsigned long long bm = __ballot(bit);
        if (lane == 0) {
            mask[(long)i*Wpad + w] = bm;
            int d = w - w0;
            if (d < 4) dq[i*4+d] = bm;
        }
    }
}

// K4: wave-specialized greedy scan, 128-row chunks. Resolver: 4-wide batch
// resolve (unchanged from R11). Acc waves: 16-bit deal slice with EIGHT named
// ulonglong2 loads (independent, wave-uniform branches, one vmcnt wait) —
// kills the serial-overflow loop that gated barrier A when a slice had >4
// kept rows. Overflow loop retained only for >8 (negligible).
__global__ __launch_bounds__((NACC+1)*64, 1) void k_scan(
    const unsigned long long* __restrict__ mask,
    const unsigned long long* __restrict__ dq,
    const int* __restrict__ nValidPtr,
    int* __restrict__ keepSorted, int N, int W, int Wpad)
{
    __shared__ unsigned long long ldsPartA[NACC+1];
    __shared__ unsigned long long ldsPartB[NACC+1];
    __shared__ unsigned long long ldsKeepLo, ldsKeepHi;
    int tid  = threadIdx.x;
    int wid  = tid >> 6;
    int lane = tid & 63;
    for (int i = tid; i < N; i += (NACC+1)*64) keepSorted[i] = 0;
    if (tid <= NACC) { ldsPartA[tid] = 0ULL; ldsPartB[tid] = 0ULL; }
    if (tid == 0) { ldsKeepLo = 0ULL; ldsKeepHi = 0ULL; }
    __syncthreads();

    int nValid  = __builtin_amdgcn_readfirstlane(nValidPtr[0]);
    int nChunks = (nValid + 127) >> 7;

    // resolver state: diagonal quads for current chunk
    unsigned long long A0=0,A1=0,A2=0,A3=0,B0=0,B1=0,B2=0,B3=0;
    unsigned long long sacc_prevA = 0ULL, sacc_prevB = 0ULL;
    if (wid == 0 && nChunks > 0) {
        int rA = lane, rB = 64 + lane;
        if (rA < N) {
            ulonglong2 a01 = *(const ulonglong2*)(dq + (size_t)rA*4);
            ulonglong2 a23 = *(const ulonglong2*)(dq + (size_t)rA*4 + 2);
            A0=a01.x; A1=a01.y; A2=a23.x; A3=a23.y;
        }
        if (rB < N) {
            ulonglong2 b01 = *(const ulonglong2*)(dq + (size_t)rB*4);
            ulonglong2 b23 = *(const ulonglong2*)(dq + (size_t)rB*4 + 2);
            B0=b01.x; B1=b01.y; B2=b23.x; B3=b23.y;
        }
    }
    // accumulator state: lane L owns words 2L, 2L+1
    unsigned long long accx = 0ULL, accy = 0ULL;
    bool accWave = (wid >= 1);
    int  accIdx  = wid - 1;                  // 0..NACC-1
    bool laneok  = (2*lane + 1 < Wpad);

    for (int c = 0; c < nChunks; ++c) {
        int base = c << 7;
        if (wid == 0) {
            // prefetch next chunk's quads (vmem, stays in flight across barriers)
            unsigned long long nA0=0,nA1=0,nA2=0,nA3=0,nB0=0,nB1=0,nB2=0,nB3=0;
            if (c + 1 < nChunks) {
                int rA = base + 128 + lane, rB = base + 192 + lane;
                if (rA < N) {
                    ulonglong2 a01 = *(const ulonglong2*)(dq + (size_t)rA*4);
                    ulonglong2 a23 = *(const ulonglong2*)(dq + (size_t)rA*4 + 2);
                    nA0=a01.x; nA1=a01.y; nA2=a23.x; nA3=a23.y;
                }
                if (rB < N) {
                    ulonglong2 b01 = *(const ulonglong2*)(dq + (size_t)rB*4);
                    ulonglong2 b23 = *(const ulonglong2*)(dq + (size_t)rB*4 + 2);
                    nB0=b01.x; nB1=b01.y; nB2=b23.x; nB3=b23.y;
                }
            }

            unsigned long long pA = sacc_prevA, pB = sacc_prevB;
#pragma unroll
            for (int k = 1; k <= NACC; ++k) { pA |= ldsPartA[k]; pB |= ldsPartB[k]; }
            unsigned long long incLo = rfl64(pA), incHi = rfl64(pB);
            int nv  = nValid - base;
            unsigned long long validLo = (nv >= 64) ? ~0ULL : ((1ULL << nv) - 1ULL);
            int nv2 = nv - 64;
            unsigned long long validHi = (nv2 >= 64) ? ~0ULL
                                        : (nv2 <= 0 ? 0ULL : ((1ULL << nv2) - 1ULL));
            unsigned long long candLo = validLo & ~incLo;
            unsigned long long candHi = validHi & ~incHi;
            unsigned long long keepLo = 0ULL, keepHi = 0ULL;

            // phase 1: 4-wide batch resolve over first-half rows
            unsigned long long mHiAcc = 0ULL;
            while (candLo) {
                unsigned long long t = candLo;
                int a0 = __builtin_ctzll(t); t &= t - 1;
                int a1 = t ? __builtin_ctzll(t) : a0; t &= t - 1;
                int a2 = t ? __builtin_ctzll(t) : a0; t &= t - 1;
                int a3 = t ? __builtin_ctzll(t) : a0;
                unsigned long long m0 = rdlane64(A0, a0), m1 = rdlane64(A0, a1);
                unsigned long long m2 = rdlane64(A0, a2), m3 = rdlane64(A0, a3);
                unsigned long long n0 = rdlane64(A1, a0), n1 = rdlane64(A1, a1);
                unsigned long long n2 = rdlane64(A1, a2), n3 = rdlane64(A1, a3);
                unsigned long long rem  = m0 | (1ULL << a0);
                unsigned long long kept = 1ULL << a0;
                unsigned long long hi   = n0;
                unsigned long long b;
                b = 1ULL << a1; if (!(rem & b)) { rem |= m1 | b; kept |= b; hi |= n1; }
                b = 1ULL << a2; if (!(rem & b)) { rem |= m2 | b; kept |= b; hi |= n2; }
                b = 1ULL << a3; if (!(rem & b)) { rem |= m3 | b; kept |= b; hi |= n3; }
                keepLo |= kept; mHiAcc |= hi;
                candLo &= ~rem;
            }
            candHi &= ~mHiAcc;
            // phase 2: 4-wide batch resolve over second-half rows
            while (candHi) {
                unsigned long long t = candHi;
                int a0 = __builtin_ctzll(t); t &= t - 1;
                int a1 = t ? __builtin_ctzll(t) : a0; t &= t - 1;
                int a2 = t ? __builtin_ctzll(t) : a0; t &= t - 1;
                int a3 = t ? __builtin_ctzll(t) : a0;
                unsigned long long m0 = rdlane64(B0, a0), m1 = rdlane64(B0, a1);
                unsigned long long m2 = rdlane64(B0, a2), m3 = rdlane64(B0, a3);
                unsigned long long rem  = m0 | (1ULL << a0);
                unsigned long long kept = 1ULL << a0;
                unsigned long long b;
                b = 1ULL << a1; if (!(rem & b)) { rem |= m1 | b; kept |= b; }
                b = 1ULL << a2; if (!(rem & b)) { rem |= m2 | b; kept |= b; }
                b = 1ULL << a3; if (!(rem & b)) { rem |= m3 | b; kept |= b; }
                keepHi |= kept;
                candHi &= ~rem;
            }
            // sacc for next chunk: masked wave-ORs (off critical chain)
            {
                unsigned long long kL = (keepLo >> lane) & 1ULL;
                unsigned long long kH = (keepHi >> lane) & 1ULL;
                unsigned long long selA = (kL ? A2 : 0ULL) | (kH ? B1 : 0ULL);
                unsigned long long selB = (kL ? A3 : 0ULL) | (kH ? B2 : 0ULL);
                sacc_prevA = waveOr64(selA);
                sacc_prevB = waveOr64(selB);
            }
            if (lane == 0) { ldsKeepLo = keepLo; ldsKeepHi = keepHi; }
            if (base + lane < N)      keepSorted[base + lane]      = (int)((keepLo >> lane) & 1ULL);
            if (base + 64 + lane < N) keepSorted[base + 64 + lane] = (int)((keepHi >> lane) & 1ULL);
            A0=nA0; A1=nA1; A2=nA2; A3=nA3; B0=nB0; B1=nB1; B2=nB2; B3=nB3;
        }
        BAR_LDS();                             // barrier A (LDS-order only)
        unsigned long long kLo = ldsKeepLo;
        unsigned long long kHi = ldsKeepHi;
        if (accWave && laneok && lane == c + 1) {  // publish words 2c+2, 2c+3
            ldsPartA[wid] = accx;
            ldsPartB[wid] = accy;
        }
        BAR_LDS();                             // barrier B
        if (accWave && laneok) {
            // 16-bit deal slice: wave accIdx owns keep bits [16k, 16k+16)
            unsigned int myb = (accIdx < 4)
                ? (unsigned int)((kLo >> (16*accIdx)) & 0xFFFFULL)
                : (unsigned int)((kHi >> (16*(accIdx-4))) & 0xFFFFULL);
            if (myb) {
                const unsigned long long* mb =
                    mask + (size_t)(base + 16*accIdx) * Wpad + 2*lane;
                unsigned int b = myb;
                int a0 = __builtin_ctz(b); b &= b - 1;
                int a1=-1,a2=-1,a3=-1,a4=-1,a5=-1,a6=-1,a7=-1;
                if (b) { a1 = __builtin_ctz(b); b &= b - 1; }
                if (b) { a2 = __builtin_ctz(b); b &= b - 1; }
                if (b) { a3 = __builtin_ctz(b); b &= b - 1; }
                if (b) { a4 = __builtin_ctz(b); b &= b - 1; }
                if (b) { a5 = __builtin_ctz(b); b &= b - 1; }
                if (b) { a6 = __builtin_ctz(b); b &= b - 1; }
                if (b) { a7 = __builtin_ctz(b); b &= b - 1; }
                ulonglong2 v0 = {0,0}, v1 = {0,0}, v2 = {0,0}, v3 = {0,0};
                ulonglong2 v4 = {0,0}, v5 = {0,0}, v6 = {0,0}, v7 = {0,0};
                v0 = *(const ulonglong2*)(mb + (size_t)a0 * Wpad);
                if (a1 >= 0) v1 = *(const ulonglong2*)(mb + (size_t)a1 * Wpad);
                if (a2 >= 0) v2 = *(const ulonglong2*)(mb + (size_t)a2 * Wpad);
                if (a3 >= 0) v3 = *(const ulonglong2*)(mb + (size_t)a3 * Wpad);
                if (a4 >= 0) v4 = *(const ulonglong2*)(mb + (size_t)a4 * Wpad);
                if (a5 >= 0) v5 = *(const ulonglong2*)(mb + (size_t)a5 * Wpad);
                if (a6 >= 0) v6 = *(const ulonglong2*)(mb + (size_t)a6 * Wpad);
                if (a7 >= 0) v7 = *(const ulonglong2*)(mb + (size_t)a7 * Wpad);
                accx |= ((v0.x|v1.x)|(v2.x|v3.x)) | ((v4.x|v5.x)|(v6.x|v7.x));
                accy |= ((v0.y|v1.y)|(v2.y|v3.y)) | ((v4.y|v5.y)|(v6.y|v7.y));
                while (b) {                    // >8 kept in this slice (negligible)
                    int a = __builtin_ctz(b); b &= b - 1;
                    ulonglong2 v = *(const ulonglong2*)(mb + (size_t)a * Wpad);
                    accx |= v.x; accy |= v.y;
                }
            }
        }
    }
}

// K5: write outputs in original order: boxes*m, score*m, float(cls*keep).
__global__ __launch_bounds__(256) void k_out(
    const float* __restrict__ boxes, const float* __restrict__ score,
    const int* __restrict__ cls, const int* __restrict__ rank,
    const int* __restrict__ keepSorted,
    float* __restrict__ out, int N)
{
    int n = blockIdx.x * blockDim.x + threadIdx.x;
    if (n >= N) return;
    int k = keepSorted[rank[n]];
    float m = (float)k;
    out[n*4+0] = boxes[n*4+0]*m;
    out[n*4+1] = boxes[n*4+1]*m;
    out[n*4+2] = boxes[n*4+2]*m;
    out[n*4+3] = boxes[n*4+3]*m;
    out[(long)N*4 + n] = score[n]*m;
    out[(long)N*5 + n] = (float)(cls[n] * k);
}

extern "C" void kernel_launch(void* const* d_in, const int* in_sizes, int n_in,
                              void* d_out, int out_size, void* d_ws, size_t ws_size,
                              hipStream_t stream) {
    const float* prop = (const float*)d_in[0];
    const float* reg  = (const float*)d_in[1];
    const float* clss = (const float*)d_in[2];
    const float* stds = (const float*)d_in[3];
    const int*   img  = (const int*)d_in[4];

    int N = in_sizes[0] / 4;
    int C = in_sizes[2] / N;
    int W = (N + 63) / 64;
    int Wpad = (W + 1) & ~1;          // even -> 16B rows

    char* ws = (char*)d_ws;
    size_t off = 0;
    float* boxes       = (float*)(ws + off); off += (size_t)N*4*sizeof(float);
    float* key         = (float*)(ws + off); off += (size_t)N*sizeof(float);
    float* score       = (float*)(ws + off); off += (size_t)N*sizeof(float);
    int*   cls         = (int*)  (ws + off); off += (size_t)N*sizeof(int);
    int*   rank        = (int*)  (ws + off); off += (size_t)N*sizeof(int);
    float* boxesSorted = (float*)(ws + off); off += (size_t)N*4*sizeof(float);
    float* areaSorted  = (float*)(ws + off); off += (size_t)N*sizeof(float);
    float* keySorted   = (float*)(ws + off); off += (size_t)N*sizeof(float);
    int*   keepSorted  = (int*)  (ws + off); off += (size_t)N*sizeof(int);
    int*   nValid      = (int*)  (ws + off); off += sizeof(int);
    off = (off + 31) & ~(size_t)31;   // 32B-align dq / mask rows
    unsigned long long* dq    = (unsigned long long*)(ws + off);
    off += (size_t)N * 4 * sizeof(unsigned long long);
    unsigned long long* mask  = (unsigned long long*)(ws + off);
    off += (size_t)N * Wpad * sizeof(unsigned long long);
    (void)ws_size; (void)out_size; (void)n_in;

    int rowBlocks  = (N + 3) / 4;
    int thrBlocks  = (N + 255) / 256;
    int rankBlocks = (N + 63) / 64;

    k_decode<<<rowBlocks, 256, 0, stream>>>(prop, reg, clss, stds, img,
                                            boxes, key, score, cls, N, C);
    k_rank<<<rankBlocks, 256, (size_t)N*sizeof(float), stream>>>(key, boxes,
                                            boxesSorted, areaSorted, keySorted, rank, nValid, N);
    k_mask<<<rowBlocks, 256, 0, stream>>>(boxesSorted, areaSorted, keySorted,
                                          mask, dq, N, W, Wpad);
    k_scan<<<1, (NACC+1)*64, 0, stream>>>(mask, dq, nValid, keepSorted, N, W, Wpad);
    k_out<<<thrBlocks, 256, 0, stream>>>(boxes, score, cls, rank, keepSorted,
                                         (float*)d_out, N);
}